// Round 1
// baseline (5936.610 us; speedup 1.0000x reference)
//
#include <hip/hip_runtime.h>

constexpr int N_NODES = 50000;
constexpr int N_EDGES = 1600000;
constexpr int E_TOT   = N_EDGES + N_NODES;   // self-loops appended
constexpr int IN_DIM  = 128;
constexpr int HEADS   = 4;
constexpr int FDIM    = 64;
constexpr int HF      = 256;                  // HEADS * FDIM
constexpr float NEG   = 0.2f;

__device__ __forceinline__ float leaky(float t) {
    return fmaxf(t, 0.f) + NEG * fminf(t, 0.f);
}

// ---------------- Kernel 1: h = x @ W  (50000x128 @ 128x256) ----------------
// 32 rows per block, 256 threads. Thread t: cols 4*(t&63)..+3, rows (t>>6)*8..+7.
__global__ __launch_bounds__(256) void gemm_kernel(const float* __restrict__ x,
                                                   const float* __restrict__ W,
                                                   float* __restrict__ h) {
    __shared__ float xs[IN_DIM * 32];  // xs[k*32 + r]  (transposed tile)
    const int t = threadIdx.x;
    const int node0 = blockIdx.x * 32;

    // stage x tile transposed: thread handles row r = t>>3, k-range (t&7)*16..+15
    {
        const int r  = t >> 3;
        const int k0 = (t & 7) * 16;
        int row = node0 + r;
        if (row >= N_NODES) row = N_NODES - 1;  // clamp (reads valid mem)
        const float4* src = reinterpret_cast<const float4*>(&x[row * IN_DIM + k0]);
        #pragma unroll
        for (int i = 0; i < 4; ++i) {
            float4 v = src[i];
            int k = k0 + i * 4;
            xs[(k + 0) * 32 + r] = v.x;
            xs[(k + 1) * 32 + r] = v.y;
            xs[(k + 2) * 32 + r] = v.z;
            xs[(k + 3) * 32 + r] = v.w;
        }
    }
    __syncthreads();

    const int c = (t & 63) * 4;    // output col
    const int g = (t >> 6) * 8;    // row base within tile (uniform per wave)
    float acc[8][4];
    #pragma unroll
    for (int r = 0; r < 8; ++r)
        #pragma unroll
        for (int j = 0; j < 4; ++j) acc[r][j] = 0.f;

    #pragma unroll 4
    for (int k = 0; k < IN_DIM; ++k) {
        const float4 wv = *reinterpret_cast<const float4*>(&W[k * HF + c]);
        const float4 xa = *reinterpret_cast<const float4*>(&xs[k * 32 + g]);
        const float4 xb = *reinterpret_cast<const float4*>(&xs[k * 32 + g + 4]);
        const float xr[8] = {xa.x, xa.y, xa.z, xa.w, xb.x, xb.y, xb.z, xb.w};
        #pragma unroll
        for (int r = 0; r < 8; ++r) {
            acc[r][0] = fmaf(xr[r], wv.x, acc[r][0]);
            acc[r][1] = fmaf(xr[r], wv.y, acc[r][1]);
            acc[r][2] = fmaf(xr[r], wv.z, acc[r][2]);
            acc[r][3] = fmaf(xr[r], wv.w, acc[r][3]);
        }
    }

    #pragma unroll
    for (int r = 0; r < 8; ++r) {
        const int row = node0 + g + r;
        if (row < N_NODES) {
            float4 v = make_float4(acc[r][0], acc[r][1], acc[r][2], acc[r][3]);
            *reinterpret_cast<float4*>(&h[row * HF + c]) = v;
        }
    }
}

// ---------------- Kernel 2: per-node attention logits ----------------
// One wave per node. lane: head = lane>>4, feat = (lane&15)*4..+3.
__global__ __launch_bounds__(256) void att_kernel(const float* __restrict__ h,
                                                  const float* __restrict__ att_src,
                                                  const float* __restrict__ att_dst,
                                                  float* __restrict__ a_s,
                                                  float* __restrict__ a_d) {
    const int wid  = (blockIdx.x * 256 + threadIdx.x) >> 6;  // node id
    const int lane = threadIdx.x & 63;
    if (wid >= N_NODES) return;
    const int hd = lane >> 4;
    const int j  = (lane & 15) * 4;
    const float4 hv = *reinterpret_cast<const float4*>(&h[wid * HF + hd * FDIM + j]);
    const float4 as = *reinterpret_cast<const float4*>(&att_src[hd * FDIM + j]);
    const float4 ad = *reinterpret_cast<const float4*>(&att_dst[hd * FDIM + j]);
    float ps = hv.x * as.x + hv.y * as.y + hv.z * as.z + hv.w * as.w;
    float pd = hv.x * ad.x + hv.y * ad.y + hv.z * ad.z + hv.w * ad.w;
    #pragma unroll
    for (int off = 1; off < 16; off <<= 1) {
        ps += __shfl_xor(ps, off);
        pd += __shfl_xor(pd, off);
    }
    if ((lane & 15) == 0) {
        a_s[wid * HEADS + hd] = ps;
        a_d[wid * HEADS + hd] = pd;
    }
}

// ---------------- Kernel 3: init out = bias, zero denominators ----------------
__global__ void init_kernel(const float* __restrict__ bias,
                            float* __restrict__ out,
                            float* __restrict__ s_sum) {
    const int i = blockIdx.x * blockDim.x + threadIdx.x;
    if (i < N_NODES * HF) out[i] = bias[i & (HF - 1)];
    if (i < N_NODES * HEADS) s_sum[i] = 0.f;
}

// ---------------- Kernel 4: softmax denominators ----------------
// One thread per edge; all 4 heads; no max-shift (logits bounded, see notes).
__global__ void score_kernel(const int* __restrict__ ei,
                             const float* __restrict__ a_s,
                             const float* __restrict__ a_d,
                             float* __restrict__ s_sum) {
    const int e = blockIdx.x * blockDim.x + threadIdx.x;
    if (e >= E_TOT) return;
    int src, dst;
    if (e < N_EDGES) { src = ei[e]; dst = ei[N_EDGES + e]; }
    else             { src = dst = e - N_EDGES; }           // self-loop
    const float4 as = *reinterpret_cast<const float4*>(&a_s[src * HEADS]);
    const float4 ad = *reinterpret_cast<const float4*>(&a_d[dst * HEADS]);
    const float ex0 = expf(leaky(as.x + ad.x));
    const float ex1 = expf(leaky(as.y + ad.y));
    const float ex2 = expf(leaky(as.z + ad.z));
    const float ex3 = expf(leaky(as.w + ad.w));
    atomicAdd(&s_sum[dst * HEADS + 0], ex0);
    atomicAdd(&s_sum[dst * HEADS + 1], ex1);
    atomicAdd(&s_sum[dst * HEADS + 2], ex2);
    atomicAdd(&s_sum[dst * HEADS + 3], ex3);
}

// ---------------- Kernel 5: weighted scatter-aggregate ----------------
// One wave per edge. lane: head = lane>>4, feat = (lane&15)*4..+3.
__global__ __launch_bounds__(256) void scatter_kernel(const int* __restrict__ ei,
                                                      const float* __restrict__ h,
                                                      const float* __restrict__ a_s,
                                                      const float* __restrict__ a_d,
                                                      const float* __restrict__ s_sum,
                                                      float* __restrict__ out) {
    const int e    = (blockIdx.x * 256 + threadIdx.x) >> 6;
    const int lane = threadIdx.x & 63;
    if (e >= E_TOT) return;
    int src, dst;
    if (e < N_EDGES) { src = ei[e]; dst = ei[N_EDGES + e]; }
    else             { src = dst = e - N_EDGES; }           // self-loop
    const int hd = lane >> 4;
    const float logit = a_s[src * HEADS + hd] + a_d[dst * HEADS + hd];
    const float ex    = expf(leaky(logit));
    const float alpha = ex / (s_sum[dst * HEADS + hd] + 1e-16f);
    const int f = (lane & 15) * 4;
    const float4 hv = *reinterpret_cast<const float4*>(&h[src * HF + hd * FDIM + f]);
    float* op = &out[dst * HF + hd * FDIM + f];
    atomicAdd(op + 0, hv.x * alpha);
    atomicAdd(op + 1, hv.y * alpha);
    atomicAdd(op + 2, hv.z * alpha);
    atomicAdd(op + 3, hv.w * alpha);
}

extern "C" void kernel_launch(void* const* d_in, const int* in_sizes, int n_in,
                              void* d_out, int out_size, void* d_ws, size_t ws_size,
                              hipStream_t stream) {
    const float* x       = (const float*)d_in[0];
    const int*   ei      = (const int*)d_in[1];   // [2, E] row-major: src then dst
    const float* W       = (const float*)d_in[2];
    const float* att_src = (const float*)d_in[3];
    const float* att_dst = (const float*)d_in[4];
    const float* bias    = (const float*)d_in[5];
    float* out = (float*)d_out;

    char* ws = (char*)d_ws;
    float* h     = (float*)(ws);                         // 50000*256*4 = 51.2 MB
    float* a_s   = (float*)(ws + 51200000);              // 0.8 MB
    float* a_d   = (float*)(ws + 52000000);              // 0.8 MB
    float* s_sum = (float*)(ws + 52800000);              // 0.8 MB

    gemm_kernel<<<(N_NODES + 31) / 32, 256, 0, stream>>>(x, W, h);
    att_kernel<<<(N_NODES + 3) / 4, 256, 0, stream>>>(h, att_src, att_dst, a_s, a_d);
    init_kernel<<<(N_NODES * HF + 255) / 256, 256, 0, stream>>>(bias, out, s_sum);
    score_kernel<<<(E_TOT + 255) / 256, 256, 0, stream>>>(ei, a_s, a_d, s_sum);
    // one wave per edge
    const long total_threads = (long)E_TOT * 64;
    scatter_kernel<<<(int)((total_threads + 255) / 256), 256, 0, stream>>>(
        ei, h, a_s, a_d, s_sum, out);
}

// Round 3
// 699.204 us; speedup vs baseline: 8.4905x; 8.4905x over previous
//
#include <hip/hip_runtime.h>

constexpr int N_NODES = 50000;
constexpr int N_EDGES = 1600000;
constexpr int E_TOT   = N_EDGES + N_NODES;   // self-loops appended
constexpr int IN_DIM  = 128;
constexpr int HEADS   = 4;
constexpr int FDIM    = 64;
constexpr int HF      = 256;                  // HEADS * FDIM
constexpr float NEG   = 0.2f;

__device__ __forceinline__ float leaky(float t) {
    return fmaxf(t, 0.f) + NEG * fminf(t, 0.f);
}

// ---------------- Kernel 1: h = x @ W  (50000x128 @ 128x256) ----------------
__global__ __launch_bounds__(256) void gemm_kernel(const float* __restrict__ x,
                                                   const float* __restrict__ W,
                                                   float* __restrict__ h) {
    __shared__ float xs[IN_DIM * 32];  // xs[k*32 + r]  (transposed tile)
    const int t = threadIdx.x;
    const int node0 = blockIdx.x * 32;

    {
        const int r  = t >> 3;
        const int k0 = (t & 7) * 16;
        int row = node0 + r;
        if (row >= N_NODES) row = N_NODES - 1;
        const float4* src = reinterpret_cast<const float4*>(&x[row * IN_DIM + k0]);
        #pragma unroll
        for (int i = 0; i < 4; ++i) {
            float4 v = src[i];
            int k = k0 + i * 4;
            xs[(k + 0) * 32 + r] = v.x;
            xs[(k + 1) * 32 + r] = v.y;
            xs[(k + 2) * 32 + r] = v.z;
            xs[(k + 3) * 32 + r] = v.w;
        }
    }
    __syncthreads();

    const int c = (t & 63) * 4;
    const int g = (t >> 6) * 8;
    float acc[8][4];
    #pragma unroll
    for (int r = 0; r < 8; ++r)
        #pragma unroll
        for (int j = 0; j < 4; ++j) acc[r][j] = 0.f;

    #pragma unroll 4
    for (int k = 0; k < IN_DIM; ++k) {
        const float4 wv = *reinterpret_cast<const float4*>(&W[k * HF + c]);
        const float4 xa = *reinterpret_cast<const float4*>(&xs[k * 32 + g]);
        const float4 xb = *reinterpret_cast<const float4*>(&xs[k * 32 + g + 4]);
        const float xr[8] = {xa.x, xa.y, xa.z, xa.w, xb.x, xb.y, xb.z, xb.w};
        #pragma unroll
        for (int r = 0; r < 8; ++r) {
            acc[r][0] = fmaf(xr[r], wv.x, acc[r][0]);
            acc[r][1] = fmaf(xr[r], wv.y, acc[r][1]);
            acc[r][2] = fmaf(xr[r], wv.z, acc[r][2]);
            acc[r][3] = fmaf(xr[r], wv.w, acc[r][3]);
        }
    }

    #pragma unroll
    for (int r = 0; r < 8; ++r) {
        const int row = node0 + g + r;
        if (row < N_NODES) {
            float4 v = make_float4(acc[r][0], acc[r][1], acc[r][2], acc[r][3]);
            *reinterpret_cast<float4*>(&h[row * HF + c]) = v;
        }
    }
}

// ---------------- Kernel 2: per-node attention logits ----------------
__global__ __launch_bounds__(256) void att_kernel(const float* __restrict__ h,
                                                  const float* __restrict__ att_src,
                                                  const float* __restrict__ att_dst,
                                                  float* __restrict__ a_s,
                                                  float* __restrict__ a_d) {
    const int wid  = (blockIdx.x * 256 + threadIdx.x) >> 6;  // node id
    const int lane = threadIdx.x & 63;
    if (wid >= N_NODES) return;
    const int hd = lane >> 4;
    const int j  = (lane & 15) * 4;
    const float4 hv = *reinterpret_cast<const float4*>(&h[wid * HF + hd * FDIM + j]);
    const float4 as = *reinterpret_cast<const float4*>(&att_src[hd * FDIM + j]);
    const float4 ad = *reinterpret_cast<const float4*>(&att_dst[hd * FDIM + j]);
    float ps = hv.x * as.x + hv.y * as.y + hv.z * as.z + hv.w * as.w;
    float pd = hv.x * ad.x + hv.y * ad.y + hv.z * ad.z + hv.w * ad.w;
    #pragma unroll
    for (int off = 1; off < 16; off <<= 1) {
        ps += __shfl_xor(ps, off);
        pd += __shfl_xor(pd, off);
    }
    if ((lane & 15) == 0) {
        a_s[wid * HEADS + hd] = ps;
        a_d[wid * HEADS + hd] = pd;
    }
}

// ---------------- Kernel 3: zero the degree counters ----------------
__global__ void zero_kernel(int* __restrict__ counts) {
    const int i = blockIdx.x * blockDim.x + threadIdx.x;
    if (i < N_NODES) counts[i] = 0;
}

// ---------------- Kernel 4: dst histogram ----------------
__global__ void hist_kernel(const int* __restrict__ ei, int* __restrict__ counts) {
    const int e = blockIdx.x * blockDim.x + threadIdx.x;
    if (e >= E_TOT) return;
    const int dst = (e < N_EDGES) ? ei[N_EDGES + e] : e - N_EDGES;
    atomicAdd(&counts[dst], 1);
}

// ---------------- Kernel 5: exclusive scan (single block) ----------------
__global__ __launch_bounds__(1024) void scan_kernel(const int* __restrict__ counts,
                                                    int* __restrict__ offsets,
                                                    int* __restrict__ cursor) {
    __shared__ int part[1024];
    const int t = threadIdx.x;
    constexpr int CH = (N_NODES + 1023) / 1024;  // 49
    const int base = t * CH;
    int sum = 0;
    for (int i = 0; i < CH; ++i) {
        const int idx = base + i;
        if (idx < N_NODES) sum += counts[idx];
    }
    part[t] = sum;
    __syncthreads();
    for (int off = 1; off < 1024; off <<= 1) {
        int v = (t >= off) ? part[t - off] : 0;
        __syncthreads();
        part[t] += v;
        __syncthreads();
    }
    int excl = part[t] - sum;   // exclusive prefix of this thread's chunk
    for (int i = 0; i < CH; ++i) {
        const int idx = base + i;
        if (idx < N_NODES) {
            offsets[idx] = excl;
            cursor[idx]  = excl;
            excl += counts[idx];
        }
    }
    if (t == 0) offsets[N_NODES] = E_TOT;
}

// ---------------- Kernel 6: fill CSR payload (src per slot) ----------------
__global__ void fill_kernel(const int* __restrict__ ei,
                            int* __restrict__ cursor,
                            int* __restrict__ sorted_src) {
    const int e = blockIdx.x * blockDim.x + threadIdx.x;
    if (e >= E_TOT) return;
    int src, dst;
    if (e < N_EDGES) { src = ei[e]; dst = ei[N_EDGES + e]; }
    else             { src = dst = e - N_EDGES; }
    const int slot = atomicAdd(&cursor[dst], 1);
    sorted_src[slot] = src;
}

// ---------------- Kernel 7: gather-aggregate, one wave per dst node --------
// lane: head = lane>>4, feat = (lane&15)*4..+3. Single pass: accumulate
// numerator (ex*h) and denominator (ex) together, divide at the end.
__global__ __launch_bounds__(256) void gather_kernel(const int* __restrict__ sorted_src,
                                                     const int* __restrict__ offsets,
                                                     const float* __restrict__ h,
                                                     const float* __restrict__ a_s,
                                                     const float* __restrict__ a_d,
                                                     const float* __restrict__ bias,
                                                     float* __restrict__ out) {
    const int dst  = (blockIdx.x * 256 + threadIdx.x) >> 6;
    const int lane = threadIdx.x & 63;
    if (dst >= N_NODES) return;
    const int hd = lane >> 4;
    const int f  = (lane & 15) * 4;
    const int beg = offsets[dst];
    const int end = offsets[dst + 1];
    const float ad = a_d[dst * HEADS + hd];

    float4 acc = make_float4(0.f, 0.f, 0.f, 0.f);
    float  dsum = 0.f;

    int j = beg;
    for (; j + 1 < end; j += 2) {     // 2-edge unroll for MLP
        const int s0 = sorted_src[j];
        const int s1 = sorted_src[j + 1];
        const float ex0 = expf(leaky(a_s[s0 * HEADS + hd] + ad));
        const float ex1 = expf(leaky(a_s[s1 * HEADS + hd] + ad));
        const float4 h0 = *reinterpret_cast<const float4*>(&h[s0 * HF + hd * FDIM + f]);
        const float4 h1 = *reinterpret_cast<const float4*>(&h[s1 * HF + hd * FDIM + f]);
        acc.x = fmaf(ex0, h0.x, acc.x); acc.y = fmaf(ex0, h0.y, acc.y);
        acc.z = fmaf(ex0, h0.z, acc.z); acc.w = fmaf(ex0, h0.w, acc.w);
        acc.x = fmaf(ex1, h1.x, acc.x); acc.y = fmaf(ex1, h1.y, acc.y);
        acc.z = fmaf(ex1, h1.z, acc.z); acc.w = fmaf(ex1, h1.w, acc.w);
        dsum += ex0 + ex1;
    }
    if (j < end) {
        const int s0 = sorted_src[j];
        const float ex0 = expf(leaky(a_s[s0 * HEADS + hd] + ad));
        const float4 h0 = *reinterpret_cast<const float4*>(&h[s0 * HF + hd * FDIM + f]);
        acc.x = fmaf(ex0, h0.x, acc.x); acc.y = fmaf(ex0, h0.y, acc.y);
        acc.z = fmaf(ex0, h0.z, acc.z); acc.w = fmaf(ex0, h0.w, acc.w);
        dsum += ex0;
    }

    const float inv = 1.f / (dsum + 1e-16f);
    const float4 bv = *reinterpret_cast<const float4*>(&bias[hd * FDIM + f]);
    float4 o;
    o.x = acc.x * inv + bv.x;
    o.y = acc.y * inv + bv.y;
    o.z = acc.z * inv + bv.z;
    o.w = acc.w * inv + bv.w;
    *reinterpret_cast<float4*>(&out[dst * HF + hd * FDIM + f]) = o;
}

extern "C" void kernel_launch(void* const* d_in, const int* in_sizes, int n_in,
                              void* d_out, int out_size, void* d_ws, size_t ws_size,
                              hipStream_t stream) {
    const float* x       = (const float*)d_in[0];
    const int*   ei      = (const int*)d_in[1];   // [2, E]: src row then dst row
    const float* W       = (const float*)d_in[2];
    const float* att_src = (const float*)d_in[3];
    const float* att_dst = (const float*)d_in[4];
    const float* bias    = (const float*)d_in[5];
    float* out = (float*)d_out;

    char* ws = (char*)d_ws;
    float* h          = (float*)(ws);                  // 51,200,000 B
    float* a_s        = (float*)(ws + 51200000);       //    800,000 B
    float* a_d        = (float*)(ws + 52000000);       //    800,000 B
    int*   counts     = (int*)  (ws + 52800000);       //    200,000 B
    int*   offsets    = (int*)  (ws + 53000000);       //    200,004 B
    int*   cursor     = (int*)  (ws + 53200016);       //    200,000 B
    int*   sorted_src = (int*)  (ws + 53400016);       //  6,600,000 B  → 60.0 MB total

    gemm_kernel<<<(N_NODES + 31) / 32, 256, 0, stream>>>(x, W, h);
    att_kernel<<<(N_NODES + 3) / 4, 256, 0, stream>>>(h, att_src, att_dst, a_s, a_d);
    zero_kernel<<<(N_NODES + 255) / 256, 256, 0, stream>>>(counts);
    hist_kernel<<<(E_TOT + 255) / 256, 256, 0, stream>>>(ei, counts);
    scan_kernel<<<1, 1024, 0, stream>>>(counts, offsets, cursor);
    fill_kernel<<<(E_TOT + 255) / 256, 256, 0, stream>>>(ei, cursor, sorted_src);
    const long total_threads = (long)N_NODES * 64;
    gather_kernel<<<(int)((total_threads + 255) / 256), 256, 0, stream>>>(
        sorted_src, offsets, h, a_s, a_d, bias, out);
}

// Round 5
// 657.430 us; speedup vs baseline: 9.0300x; 1.0635x over previous
//
#include <hip/hip_runtime.h>

constexpr int N_NODES = 50000;
constexpr int N_EDGES = 1600000;
constexpr int E_TOT   = N_EDGES + N_NODES;   // self-loops appended
constexpr int IN_DIM  = 128;
constexpr int HEADS   = 4;
constexpr int FDIM    = 64;
constexpr int HF      = 256;                  // HEADS * FDIM
constexpr float NEG   = 0.2f;

__device__ __forceinline__ float leaky(float t) {
    return fmaxf(t, 0.f) + NEG * fminf(t, 0.f);
}

// ---------------- Kernel 1: h = x @ W  (50000x128 @ 128x256) ----------------
// 64 rows per block; x-tile in LDS; thread t: cols 4*(t&63)..+3, rows (t>>6)*16..+15.
// W read once per block from L2 (782 blocks x 128KB = 100 MB L2 traffic).
__global__ __launch_bounds__(256) void gemm_kernel(const float* __restrict__ x,
                                                   const float* __restrict__ W,
                                                   float* __restrict__ h) {
    __shared__ float xs[IN_DIM][64];   // 32 KB, xs[k][row]
    const int t = threadIdx.x;
    const int node0 = blockIdx.x * 64;

    // stage: thread t loads row (t&63), k-range (t>>6)*32 .. +31 (8 float4)
    {
        const int r  = t & 63;
        const int k0 = (t >> 6) * 32;
        int row = node0 + r;
        if (row >= N_NODES) row = N_NODES - 1;   // clamp (valid mem)
        const float4* src = reinterpret_cast<const float4*>(&x[row * IN_DIM + k0]);
        #pragma unroll
        for (int i = 0; i < 8; ++i) {
            float4 v = src[i];
            int k = k0 + i * 4;
            xs[k + 0][r] = v.x;   // bank = r%32 -> 2-way across wave: free
            xs[k + 1][r] = v.y;
            xs[k + 2][r] = v.z;
            xs[k + 3][r] = v.w;
        }
    }
    __syncthreads();

    const int c  = (t & 63) * 4;    // output col
    const int rg = (t >> 6) * 16;   // row base (wave-uniform)
    float acc[16][4];
    #pragma unroll
    for (int r = 0; r < 16; ++r)
        #pragma unroll
        for (int j = 0; j < 4; ++j) acc[r][j] = 0.f;

    #pragma unroll 2
    for (int k = 0; k < IN_DIM; ++k) {
        const float4 wv = *reinterpret_cast<const float4*>(&W[k * HF + c]);
        const float4 xa = *reinterpret_cast<const float4*>(&xs[k][rg + 0]);   // broadcast
        const float4 xb = *reinterpret_cast<const float4*>(&xs[k][rg + 4]);
        const float4 xc = *reinterpret_cast<const float4*>(&xs[k][rg + 8]);
        const float4 xd = *reinterpret_cast<const float4*>(&xs[k][rg + 12]);
        const float xr[16] = {xa.x, xa.y, xa.z, xa.w, xb.x, xb.y, xb.z, xb.w,
                              xc.x, xc.y, xc.z, xc.w, xd.x, xd.y, xd.z, xd.w};
        #pragma unroll
        for (int r = 0; r < 16; ++r) {
            acc[r][0] = fmaf(xr[r], wv.x, acc[r][0]);
            acc[r][1] = fmaf(xr[r], wv.y, acc[r][1]);
            acc[r][2] = fmaf(xr[r], wv.z, acc[r][2]);
            acc[r][3] = fmaf(xr[r], wv.w, acc[r][3]);
        }
    }

    #pragma unroll
    for (int r = 0; r < 16; ++r) {
        const int row = node0 + rg + r;
        if (row < N_NODES) {
            float4 v = make_float4(acc[r][0], acc[r][1], acc[r][2], acc[r][3]);
            *reinterpret_cast<float4*>(&h[row * HF + c]) = v;
        }
    }
}

// ---------------- Kernel 2: per-node attention logits ----------------
__global__ __launch_bounds__(256) void att_kernel(const float* __restrict__ h,
                                                  const float* __restrict__ att_src,
                                                  const float* __restrict__ att_dst,
                                                  float* __restrict__ a_s,
                                                  float* __restrict__ a_d) {
    const int wid  = (blockIdx.x * 256 + threadIdx.x) >> 6;  // node id
    const int lane = threadIdx.x & 63;
    if (wid >= N_NODES) return;
    const int hd = lane >> 4;
    const int j  = (lane & 15) * 4;
    const float4 hv = *reinterpret_cast<const float4*>(&h[wid * HF + hd * FDIM + j]);
    const float4 as = *reinterpret_cast<const float4*>(&att_src[hd * FDIM + j]);
    const float4 ad = *reinterpret_cast<const float4*>(&att_dst[hd * FDIM + j]);
    float ps = hv.x * as.x + hv.y * as.y + hv.z * as.z + hv.w * as.w;
    float pd = hv.x * ad.x + hv.y * ad.y + hv.z * ad.z + hv.w * ad.w;
    #pragma unroll
    for (int off = 1; off < 16; off <<= 1) {
        ps += __shfl_xor(ps, off);
        pd += __shfl_xor(pd, off);
    }
    if ((lane & 15) == 0) {
        a_s[wid * HEADS + hd] = ps;
        a_d[wid * HEADS + hd] = pd;
    }
}

// ---------------- Kernel 3: zero the degree counters ----------------
__global__ void zero_kernel(int* __restrict__ counts) {
    const int i = blockIdx.x * blockDim.x + threadIdx.x;
    if (i < N_NODES) counts[i] = 0;
}

// ---------------- Kernel 4: dst histogram ----------------
__global__ void hist_kernel(const int* __restrict__ ei, int* __restrict__ counts) {
    const int e = blockIdx.x * blockDim.x + threadIdx.x;
    if (e >= E_TOT) return;
    const int dst = (e < N_EDGES) ? ei[N_EDGES + e] : e - N_EDGES;
    atomicAdd(&counts[dst], 1);
}

// ---------------- Kernel 5: exclusive scan (single block) ----------------
__global__ __launch_bounds__(1024) void scan_kernel(const int* __restrict__ counts,
                                                    int* __restrict__ offsets,
                                                    int* __restrict__ cursor) {
    __shared__ int part[1024];
    const int t = threadIdx.x;
    constexpr int CH = (N_NODES + 1023) / 1024;  // 49
    const int base = t * CH;
    int sum = 0;
    for (int i = 0; i < CH; ++i) {
        const int idx = base + i;
        if (idx < N_NODES) sum += counts[idx];
    }
    part[t] = sum;
    __syncthreads();
    for (int off = 1; off < 1024; off <<= 1) {
        int v = (t >= off) ? part[t - off] : 0;
        __syncthreads();
        part[t] += v;
        __syncthreads();
    }
    int excl = part[t] - sum;   // exclusive prefix of this thread's chunk
    for (int i = 0; i < CH; ++i) {
        const int idx = base + i;
        if (idx < N_NODES) {
            offsets[idx] = excl;
            cursor[idx]  = excl;
            excl += counts[idx];
        }
    }
    if (t == 0) offsets[N_NODES] = E_TOT;
}

// ---------------- Kernel 6: fill CSR payload: src + precomputed exp-scores --
__global__ void fill_kernel(const int* __restrict__ ei,
                            const float* __restrict__ a_s,
                            const float* __restrict__ a_d,
                            int* __restrict__ cursor,
                            int* __restrict__ sorted_src,
                            float4* __restrict__ sorted_ex) {
    const int e = blockIdx.x * blockDim.x + threadIdx.x;
    if (e >= E_TOT) return;
    int src, dst;
    if (e < N_EDGES) { src = ei[e]; dst = ei[N_EDGES + e]; }
    else             { src = dst = e - N_EDGES; }
    const float4 as = *reinterpret_cast<const float4*>(&a_s[src * HEADS]);
    const float4 ad = *reinterpret_cast<const float4*>(&a_d[dst * HEADS]);
    float4 ex;
    ex.x = expf(leaky(as.x + ad.x));
    ex.y = expf(leaky(as.y + ad.y));
    ex.z = expf(leaky(as.z + ad.z));
    ex.w = expf(leaky(as.w + ad.w));
    const int slot = atomicAdd(&cursor[dst], 1);
    sorted_src[slot] = src;
    sorted_ex[slot]  = ex;
}

// ---------------- Kernel 7: gather-aggregate, one wave per dst node --------
// lane: head = lane>>4, feat = (lane&15)*4..+3. Exp precomputed; src indices
// scalarized via readfirstlane so h addresses use SGPR bases. 4-edge unroll.
__global__ __launch_bounds__(256) void gather_kernel(const int* __restrict__ sorted_src,
                                                     const float* __restrict__ sorted_ex,
                                                     const int* __restrict__ offsets,
                                                     const float* __restrict__ h,
                                                     const float* __restrict__ bias,
                                                     float* __restrict__ out) {
    const int dst  = (blockIdx.x * 256 + threadIdx.x) >> 6;
    const int lane = threadIdx.x & 63;
    if (dst >= N_NODES) return;
    const int hd   = lane >> 4;
    const int lofs = hd * FDIM + (lane & 15) * 4;   // per-lane offset in h row

    const int beg = __builtin_amdgcn_readfirstlane(offsets[dst]);
    const int end = __builtin_amdgcn_readfirstlane(offsets[dst + 1]);

    float4 acc = make_float4(0.f, 0.f, 0.f, 0.f);
    float  dsum = 0.f;

    int j = beg;
    for (; j + 3 < end; j += 4) {
        const int s0 = __builtin_amdgcn_readfirstlane(sorted_src[j + 0]);
        const int s1 = __builtin_amdgcn_readfirstlane(sorted_src[j + 1]);
        const int s2 = __builtin_amdgcn_readfirstlane(sorted_src[j + 2]);
        const int s3 = __builtin_amdgcn_readfirstlane(sorted_src[j + 3]);
        const float e0 = sorted_ex[(j + 0) * 4 + hd];
        const float e1 = sorted_ex[(j + 1) * 4 + hd];
        const float e2 = sorted_ex[(j + 2) * 4 + hd];
        const float e3 = sorted_ex[(j + 3) * 4 + hd];
        const float4 h0 = *reinterpret_cast<const float4*>(&h[s0 * HF + lofs]);
        const float4 h1 = *reinterpret_cast<const float4*>(&h[s1 * HF + lofs]);
        const float4 h2 = *reinterpret_cast<const float4*>(&h[s2 * HF + lofs]);
        const float4 h3 = *reinterpret_cast<const float4*>(&h[s3 * HF + lofs]);
        acc.x = fmaf(e0, h0.x, acc.x); acc.y = fmaf(e0, h0.y, acc.y);
        acc.z = fmaf(e0, h0.z, acc.z); acc.w = fmaf(e0, h0.w, acc.w);
        acc.x = fmaf(e1, h1.x, acc.x); acc.y = fmaf(e1, h1.y, acc.y);
        acc.z = fmaf(e1, h1.z, acc.z); acc.w = fmaf(e1, h1.w, acc.w);
        acc.x = fmaf(e2, h2.x, acc.x); acc.y = fmaf(e2, h2.y, acc.y);
        acc.z = fmaf(e2, h2.z, acc.z); acc.w = fmaf(e2, h2.w, acc.w);
        acc.x = fmaf(e3, h3.x, acc.x); acc.y = fmaf(e3, h3.y, acc.y);
        acc.z = fmaf(e3, h3.z, acc.z); acc.w = fmaf(e3, h3.w, acc.w);
        dsum += (e0 + e1) + (e2 + e3);
    }
    for (; j < end; ++j) {
        const int   s0 = __builtin_amdgcn_readfirstlane(sorted_src[j]);
        const float e0 = sorted_ex[j * 4 + hd];
        const float4 h0 = *reinterpret_cast<const float4*>(&h[s0 * HF + lofs]);
        acc.x = fmaf(e0, h0.x, acc.x); acc.y = fmaf(e0, h0.y, acc.y);
        acc.z = fmaf(e0, h0.z, acc.z); acc.w = fmaf(e0, h0.w, acc.w);
        dsum += e0;
    }

    const float inv = 1.f / (dsum + 1e-16f);
    const float4 bv = *reinterpret_cast<const float4*>(&bias[lofs]);
    float4 o;
    o.x = acc.x * inv + bv.x;
    o.y = acc.y * inv + bv.y;
    o.z = acc.z * inv + bv.z;
    o.w = acc.w * inv + bv.w;
    *reinterpret_cast<float4*>(&out[dst * HF + lofs]) = o;
}

extern "C" void kernel_launch(void* const* d_in, const int* in_sizes, int n_in,
                              void* d_out, int out_size, void* d_ws, size_t ws_size,
                              hipStream_t stream) {
    const float* x       = (const float*)d_in[0];
    const int*   ei      = (const int*)d_in[1];   // [2, E]: src row then dst row
    const float* W       = (const float*)d_in[2];
    const float* att_src = (const float*)d_in[3];
    const float* att_dst = (const float*)d_in[4];
    const float* bias    = (const float*)d_in[5];
    float* out = (float*)d_out;

    char* ws = (char*)d_ws;
    float*  h          = (float*) (ws);                  // 51,200,000 B
    float*  a_s        = (float*) (ws + 51200000);       //    800,000 B
    float*  a_d        = (float*) (ws + 52000000);       //    800,000 B
    int*    counts     = (int*)   (ws + 52800000);       //    200,000 B
    int*    offsets    = (int*)   (ws + 53000000);       //    200,004 B
    int*    cursor     = (int*)   (ws + 53200016);       //    200,000 B
    int*    sorted_src = (int*)   (ws + 53400016);       //  6,600,000 B
    float4* sorted_ex  = (float4*)(ws + 60000016);       // 26,400,000 B → 86.4 MB total

    gemm_kernel<<<(N_NODES + 63) / 64, 256, 0, stream>>>(x, W, h);
    att_kernel<<<(N_NODES + 3) / 4, 256, 0, stream>>>(h, att_src, att_dst, a_s, a_d);
    zero_kernel<<<(N_NODES + 255) / 256, 256, 0, stream>>>(counts);
    hist_kernel<<<(E_TOT + 255) / 256, 256, 0, stream>>>(ei, counts);
    scan_kernel<<<1, 1024, 0, stream>>>(counts, offsets, cursor);
    fill_kernel<<<(E_TOT + 255) / 256, 256, 0, stream>>>(ei, a_s, a_d, cursor,
                                                         sorted_src, sorted_ex);
    const long total_threads = (long)N_NODES * 64;
    gather_kernel<<<(int)((total_threads + 255) / 256), 256, 0, stream>>>(
        sorted_src, (const float*)sorted_ex, offsets, h, bias, out);
}

// Round 6
// 526.709 us; speedup vs baseline: 11.2711x; 1.2482x over previous
//
#include <hip/hip_runtime.h>

constexpr int N_NODES = 50000;
constexpr int N_EDGES = 1600000;
constexpr int E_TOT   = N_EDGES + N_NODES;   // self-loops appended
constexpr int IN_DIM  = 128;
constexpr int HEADS   = 4;
constexpr int FDIM    = 64;
constexpr int HF      = 256;                  // HEADS * FDIM
constexpr float NEG   = 0.2f;

__device__ __forceinline__ float leaky(float t) {
    return fmaxf(t, 0.f) + NEG * fminf(t, 0.f);
}

__device__ __forceinline__ unsigned short f2bf(float f) {   // RNE bf16
    unsigned int u = __float_as_uint(f);
    u += 0x7fffu + ((u >> 16) & 1u);
    return (unsigned short)(u >> 16);
}
__device__ __forceinline__ float bf_lo(unsigned int u) {    // low bf16 of packed pair
    return __uint_as_float(u << 16);
}
__device__ __forceinline__ float bf_hi(unsigned int u) {    // high bf16
    return __uint_as_float(u & 0xffff0000u);
}

// ---- Kernel 1: h = x @ W, fused att logits; h stored as bf16 --------------
// 64 rows/block; thread t: cols 4*(t&63)..+3, rows (t>>6)*16..+15.
// Wave w holds 16 COMPLETE rows (lane l = cols 4l..4l+3) -> in-wave att reduce.
__global__ __launch_bounds__(256) void gemm_kernel(const float* __restrict__ x,
                                                   const float* __restrict__ W,
                                                   const float* __restrict__ att_src,
                                                   const float* __restrict__ att_dst,
                                                   unsigned short* __restrict__ h_bf,
                                                   float* __restrict__ a_s,
                                                   float* __restrict__ a_d) {
    __shared__ float xs[IN_DIM][64];   // 32 KB, xs[k][row]
    const int t = threadIdx.x;
    const int node0 = blockIdx.x * 64;

    {   // stage: thread t loads row (t&63), k-range (t>>6)*32 .. +31
        const int r  = t & 63;
        const int k0 = (t >> 6) * 32;
        int row = node0 + r;
        if (row >= N_NODES) row = N_NODES - 1;   // clamp (valid mem)
        const float4* src = reinterpret_cast<const float4*>(&x[row * IN_DIM + k0]);
        #pragma unroll
        for (int i = 0; i < 8; ++i) {
            float4 v = src[i];
            int k = k0 + i * 4;
            xs[k + 0][r] = v.x;
            xs[k + 1][r] = v.y;
            xs[k + 2][r] = v.z;
            xs[k + 3][r] = v.w;
        }
    }
    __syncthreads();

    const int l  = t & 63;          // lane
    const int c  = l * 4;           // output col
    const int rg = (t >> 6) * 16;   // row base (wave-uniform)
    float acc[16][4];
    #pragma unroll
    for (int r = 0; r < 16; ++r)
        #pragma unroll
        for (int j = 0; j < 4; ++j) acc[r][j] = 0.f;

    #pragma unroll 2
    for (int k = 0; k < IN_DIM; ++k) {
        const float4 wv = *reinterpret_cast<const float4*>(&W[k * HF + c]);
        const float4 xa = *reinterpret_cast<const float4*>(&xs[k][rg + 0]);
        const float4 xb = *reinterpret_cast<const float4*>(&xs[k][rg + 4]);
        const float4 xc = *reinterpret_cast<const float4*>(&xs[k][rg + 8]);
        const float4 xd = *reinterpret_cast<const float4*>(&xs[k][rg + 12]);
        const float xr[16] = {xa.x, xa.y, xa.z, xa.w, xb.x, xb.y, xb.z, xb.w,
                              xc.x, xc.y, xc.z, xc.w, xd.x, xd.y, xd.z, xd.w};
        #pragma unroll
        for (int r = 0; r < 16; ++r) {
            acc[r][0] = fmaf(xr[r], wv.x, acc[r][0]);
            acc[r][1] = fmaf(xr[r], wv.y, acc[r][1]);
            acc[r][2] = fmaf(xr[r], wv.z, acc[r][2]);
            acc[r][3] = fmaf(xr[r], wv.w, acc[r][3]);
        }
    }

    // att epilogue: per row, 16-lane dot-reduce (head = l>>4 matches col range)
    const float4 asv = *reinterpret_cast<const float4*>(&att_src[c]);
    const float4 adv = *reinterpret_cast<const float4*>(&att_dst[c]);
    #pragma unroll
    for (int r = 0; r < 16; ++r) {
        float ps = acc[r][0] * asv.x + acc[r][1] * asv.y +
                   acc[r][2] * asv.z + acc[r][3] * asv.w;
        float pd = acc[r][0] * adv.x + acc[r][1] * adv.y +
                   acc[r][2] * adv.z + acc[r][3] * adv.w;
        #pragma unroll
        for (int off = 1; off < 16; off <<= 1) {
            ps += __shfl_xor(ps, off);
            pd += __shfl_xor(pd, off);
        }
        const int node = node0 + rg + r;
        if ((l & 15) == 0 && node < N_NODES) {
            a_s[node * HEADS + (l >> 4)] = ps;
            a_d[node * HEADS + (l >> 4)] = pd;
        }
    }

    // bf16 store of h
    #pragma unroll
    for (int r = 0; r < 16; ++r) {
        const int node = node0 + rg + r;
        if (node < N_NODES) {
            ushort4 v;
            v.x = f2bf(acc[r][0]); v.y = f2bf(acc[r][1]);
            v.z = f2bf(acc[r][2]); v.w = f2bf(acc[r][3]);
            *reinterpret_cast<ushort4*>(&h_bf[node * HF + c]) = v;
        }
    }
}

// ---------------- Kernel 2: zero the degree counters ----------------
__global__ void zero_kernel(int* __restrict__ counts) {
    const int i = blockIdx.x * blockDim.x + threadIdx.x;
    if (i < N_NODES) counts[i] = 0;
}

// ---------------- Kernel 3: dst histogram ----------------
__global__ void hist_kernel(const int* __restrict__ ei, int* __restrict__ counts) {
    const int e = blockIdx.x * blockDim.x + threadIdx.x;
    if (e >= E_TOT) return;
    const int dst = (e < N_EDGES) ? ei[N_EDGES + e] : e - N_EDGES;
    atomicAdd(&counts[dst], 1);
}

// ---------------- Kernel 4: exclusive scan (single block) ----------------
__global__ __launch_bounds__(1024) void scan_kernel(const int* __restrict__ counts,
                                                    int* __restrict__ offsets,
                                                    int* __restrict__ cursor) {
    __shared__ int part[1024];
    const int t = threadIdx.x;
    constexpr int CH = (N_NODES + 1023) / 1024;  // 49
    const int base = t * CH;
    int sum = 0;
    for (int i = 0; i < CH; ++i) {
        const int idx = base + i;
        if (idx < N_NODES) sum += counts[idx];
    }
    part[t] = sum;
    __syncthreads();
    for (int off = 1; off < 1024; off <<= 1) {
        int v = (t >= off) ? part[t - off] : 0;
        __syncthreads();
        part[t] += v;
        __syncthreads();
    }
    int excl = part[t] - sum;
    for (int i = 0; i < CH; ++i) {
        const int idx = base + i;
        if (idx < N_NODES) {
            offsets[idx] = excl;
            cursor[idx]  = excl;
            excl += counts[idx];
        }
    }
    if (t == 0) offsets[N_NODES] = E_TOT;
}

// ---------------- Kernel 5: fill CSR payload: src + exp-scores ----------------
__global__ void fill_kernel(const int* __restrict__ ei,
                            const float* __restrict__ a_s,
                            const float* __restrict__ a_d,
                            int* __restrict__ cursor,
                            int* __restrict__ sorted_src,
                            float4* __restrict__ sorted_ex) {
    const int e = blockIdx.x * blockDim.x + threadIdx.x;
    if (e >= E_TOT) return;
    int src, dst;
    if (e < N_EDGES) { src = ei[e]; dst = ei[N_EDGES + e]; }
    else             { src = dst = e - N_EDGES; }
    const float4 as = *reinterpret_cast<const float4*>(&a_s[src * HEADS]);
    const float4 ad = *reinterpret_cast<const float4*>(&a_d[dst * HEADS]);
    float4 ex;
    ex.x = expf(leaky(as.x + ad.x));
    ex.y = expf(leaky(as.y + ad.y));
    ex.z = expf(leaky(as.z + ad.z));
    ex.w = expf(leaky(as.w + ad.w));
    const int slot = atomicAdd(&cursor[dst], 1);
    sorted_src[slot] = src;
    sorted_ex[slot]  = ex;
}

// ---------------- Kernel 6: gather-aggregate, one wave per dst, 2 edges/round
// bf16 h rows are 512B -> 32 lanes per edge; half = lane>>5 picks edge j+half.
// lane (il=lane&31) covers feats il*8..il*8+7 (head = il>>3).
__global__ __launch_bounds__(256) void gather_kernel(const int* __restrict__ sorted_src,
                                                     const float* __restrict__ sorted_ex,
                                                     const int* __restrict__ offsets,
                                                     const unsigned short* __restrict__ h_bf,
                                                     const float* __restrict__ bias,
                                                     float* __restrict__ out) {
    const int dst  = (blockIdx.x * 256 + threadIdx.x) >> 6;
    const int lane = threadIdx.x & 63;
    if (dst >= N_NODES) return;
    const int half = lane >> 5;
    const int il   = lane & 31;
    const int hd   = il >> 3;

    const int beg = __builtin_amdgcn_readfirstlane(offsets[dst]);
    const int end = __builtin_amdgcn_readfirstlane(offsets[dst + 1]);

    float a0 = 0.f, a1 = 0.f, a2 = 0.f, a3 = 0.f;
    float a4 = 0.f, a5 = 0.f, a6 = 0.f, a7 = 0.f;
    float dsum = 0.f;

    auto body = [&](int slot) {
        const int   src = sorted_src[slot];
        const float ex  = sorted_ex[slot * 4 + hd];
        const uint4 hv  = *reinterpret_cast<const uint4*>(&h_bf[src * HF + il * 8]);
        a0 = fmaf(ex, bf_lo(hv.x), a0); a1 = fmaf(ex, bf_hi(hv.x), a1);
        a2 = fmaf(ex, bf_lo(hv.y), a2); a3 = fmaf(ex, bf_hi(hv.y), a3);
        a4 = fmaf(ex, bf_lo(hv.z), a4); a5 = fmaf(ex, bf_hi(hv.z), a5);
        a6 = fmaf(ex, bf_lo(hv.w), a6); a7 = fmaf(ex, bf_hi(hv.w), a7);
        dsum += ex;
    };

    int j = beg;
    for (; j + 3 < end; j += 4) {        // 4 edges per iteration (2 per half)
        body(j + half);
        body(j + 2 + half);
    }
    for (; j + 1 < end; j += 2) body(j + half);
    if (j < end && half == 0) body(j);   // odd tail: half 0 only

    // combine the two halves (edge partition), per-head denominator included
    a0 += __shfl_xor(a0, 32); a1 += __shfl_xor(a1, 32);
    a2 += __shfl_xor(a2, 32); a3 += __shfl_xor(a3, 32);
    a4 += __shfl_xor(a4, 32); a5 += __shfl_xor(a5, 32);
    a6 += __shfl_xor(a6, 32); a7 += __shfl_xor(a7, 32);
    dsum += __shfl_xor(dsum, 32);

    const float inv = 1.f / (dsum + 1e-16f);
    const int eo = il * 8 + half * 4;    // element offset within row
    const float4 bv = *reinterpret_cast<const float4*>(&bias[eo]);
    float4 o;
    o.x = (half ? a4 : a0) * inv + bv.x;
    o.y = (half ? a5 : a1) * inv + bv.y;
    o.z = (half ? a6 : a2) * inv + bv.z;
    o.w = (half ? a7 : a3) * inv + bv.w;
    *reinterpret_cast<float4*>(&out[dst * HF + eo]) = o;
}

extern "C" void kernel_launch(void* const* d_in, const int* in_sizes, int n_in,
                              void* d_out, int out_size, void* d_ws, size_t ws_size,
                              hipStream_t stream) {
    const float* x       = (const float*)d_in[0];
    const int*   ei      = (const int*)d_in[1];   // [2, E]: src row then dst row
    const float* W       = (const float*)d_in[2];
    const float* att_src = (const float*)d_in[3];
    const float* att_dst = (const float*)d_in[4];
    const float* bias    = (const float*)d_in[5];
    float* out = (float*)d_out;

    char* ws = (char*)d_ws;
    unsigned short* h_bf = (unsigned short*)(ws);        // 25,600,000 B
    float*  a_s        = (float*) (ws + 25600000);       //    800,000 B
    float*  a_d        = (float*) (ws + 26400000);       //    800,000 B
    int*    counts     = (int*)   (ws + 27200000);       //    200,000 B
    int*    offsets    = (int*)   (ws + 27400000);       //    200,004 B
    int*    cursor     = (int*)   (ws + 27600016);       //    200,000 B
    int*    sorted_src = (int*)   (ws + 27800016);       //  6,600,000 B
    float4* sorted_ex  = (float4*)(ws + 34400016);       // 26,400,000 B → 60.8 MB total

    gemm_kernel<<<(N_NODES + 63) / 64, 256, 0, stream>>>(x, W, att_src, att_dst,
                                                         h_bf, a_s, a_d);
    zero_kernel<<<(N_NODES + 255) / 256, 256, 0, stream>>>(counts);
    hist_kernel<<<(E_TOT + 255) / 256, 256, 0, stream>>>(ei, counts);
    scan_kernel<<<1, 1024, 0, stream>>>(counts, offsets, cursor);
    fill_kernel<<<(E_TOT + 255) / 256, 256, 0, stream>>>(ei, a_s, a_d, cursor,
                                                         sorted_src, sorted_ex);
    const long total_threads = (long)N_NODES * 64;
    gather_kernel<<<(int)((total_threads + 255) / 256), 256, 0, stream>>>(
        sorted_src, (const float*)sorted_ex, offsets, h_bf, bias, out);
}

// Round 7
// 439.587 us; speedup vs baseline: 13.5050x; 1.1982x over previous
//
#include <hip/hip_runtime.h>

constexpr int N_NODES = 50000;
constexpr int N_EDGES = 1600000;
constexpr int E_TOT   = N_EDGES + N_NODES;   // self-loops appended
constexpr int IN_DIM  = 128;
constexpr int HEADS   = 4;
constexpr int FDIM    = 64;
constexpr int HF      = 256;                  // HEADS * FDIM
constexpr float NEG   = 0.2f;
constexpr int NB_SCAN = (N_NODES + 255) / 256;  // 196 scan blocks

__device__ __forceinline__ float leaky(float t) {
    return fmaxf(t, 0.f) + NEG * fminf(t, 0.f);
}

__device__ __forceinline__ unsigned short f2bf(float f) {   // RNE bf16
    unsigned int u = __float_as_uint(f);
    u += 0x7fffu + ((u >> 16) & 1u);
    return (unsigned short)(u >> 16);
}
__device__ __forceinline__ float bf_lo(unsigned int u) {
    return __uint_as_float(u << 16);
}
__device__ __forceinline__ float bf_hi(unsigned int u) {
    return __uint_as_float(u & 0xffff0000u);
}

__device__ __forceinline__ int wave_incl_scan(int v, int lane) {
    #pragma unroll
    for (int off = 1; off < 64; off <<= 1) {
        int n = __shfl_up(v, off);
        if (lane >= off) v += n;
    }
    return v;
}

// ---- Kernel 1: h = x @ W, fused att logits; h stored as bf16 --------------
__global__ __launch_bounds__(256) void gemm_kernel(const float* __restrict__ x,
                                                   const float* __restrict__ W,
                                                   const float* __restrict__ att_src,
                                                   const float* __restrict__ att_dst,
                                                   unsigned short* __restrict__ h_bf,
                                                   float* __restrict__ a_s,
                                                   float* __restrict__ a_d) {
    __shared__ float xs[IN_DIM][64];   // 32 KB, xs[k][row]
    const int t = threadIdx.x;
    const int node0 = blockIdx.x * 64;

    {   // stage: thread t loads row (t&63), k-range (t>>6)*32 .. +31
        const int r  = t & 63;
        const int k0 = (t >> 6) * 32;
        int row = node0 + r;
        if (row >= N_NODES) row = N_NODES - 1;   // clamp (valid mem)
        const float4* src = reinterpret_cast<const float4*>(&x[row * IN_DIM + k0]);
        #pragma unroll
        for (int i = 0; i < 8; ++i) {
            float4 v = src[i];
            int k = k0 + i * 4;
            xs[k + 0][r] = v.x;
            xs[k + 1][r] = v.y;
            xs[k + 2][r] = v.z;
            xs[k + 3][r] = v.w;
        }
    }
    __syncthreads();

    const int l  = t & 63;          // lane
    const int c  = l * 4;           // output col
    const int rg = (t >> 6) * 16;   // row base (wave-uniform)
    float acc[16][4];
    #pragma unroll
    for (int r = 0; r < 16; ++r)
        #pragma unroll
        for (int j = 0; j < 4; ++j) acc[r][j] = 0.f;

    #pragma unroll 2
    for (int k = 0; k < IN_DIM; ++k) {
        const float4 wv = *reinterpret_cast<const float4*>(&W[k * HF + c]);
        const float4 xa = *reinterpret_cast<const float4*>(&xs[k][rg + 0]);
        const float4 xb = *reinterpret_cast<const float4*>(&xs[k][rg + 4]);
        const float4 xc = *reinterpret_cast<const float4*>(&xs[k][rg + 8]);
        const float4 xd = *reinterpret_cast<const float4*>(&xs[k][rg + 12]);
        const float xr[16] = {xa.x, xa.y, xa.z, xa.w, xb.x, xb.y, xb.z, xb.w,
                              xc.x, xc.y, xc.z, xc.w, xd.x, xd.y, xd.z, xd.w};
        #pragma unroll
        for (int r = 0; r < 16; ++r) {
            acc[r][0] = fmaf(xr[r], wv.x, acc[r][0]);
            acc[r][1] = fmaf(xr[r], wv.y, acc[r][1]);
            acc[r][2] = fmaf(xr[r], wv.z, acc[r][2]);
            acc[r][3] = fmaf(xr[r], wv.w, acc[r][3]);
        }
    }

    // att epilogue: per row, 16-lane dot-reduce (head = l>>4 matches col range)
    const float4 asv = *reinterpret_cast<const float4*>(&att_src[c]);
    const float4 adv = *reinterpret_cast<const float4*>(&att_dst[c]);
    #pragma unroll
    for (int r = 0; r < 16; ++r) {
        float ps = acc[r][0] * asv.x + acc[r][1] * asv.y +
                   acc[r][2] * asv.z + acc[r][3] * asv.w;
        float pd = acc[r][0] * adv.x + acc[r][1] * adv.y +
                   acc[r][2] * adv.z + acc[r][3] * adv.w;
        #pragma unroll
        for (int off = 1; off < 16; off <<= 1) {
            ps += __shfl_xor(ps, off);
            pd += __shfl_xor(pd, off);
        }
        const int node = node0 + rg + r;
        if ((l & 15) == 0 && node < N_NODES) {
            a_s[node * HEADS + (l >> 4)] = ps;
            a_d[node * HEADS + (l >> 4)] = pd;
        }
    }

    // bf16 store of h
    #pragma unroll
    for (int r = 0; r < 16; ++r) {
        const int node = node0 + rg + r;
        if (node < N_NODES) {
            ushort4 v;
            v.x = f2bf(acc[r][0]); v.y = f2bf(acc[r][1]);
            v.z = f2bf(acc[r][2]); v.w = f2bf(acc[r][3]);
            *reinterpret_cast<ushort4*>(&h_bf[node * HF + c]) = v;
        }
    }
}

// ---------------- Kernel 2: zero the degree counters ----------------
__global__ void zero_kernel(int* __restrict__ counts) {
    const int i = blockIdx.x * blockDim.x + threadIdx.x;
    if (i < N_NODES) counts[i] = 0;
}

// ---------------- Kernel 3: dst histogram ----------------
__global__ void hist_kernel(const int* __restrict__ ei, int* __restrict__ counts) {
    const int e = blockIdx.x * blockDim.x + threadIdx.x;
    if (e >= E_TOT) return;
    const int dst = (e < N_EDGES) ? ei[N_EDGES + e] : e - N_EDGES;
    atomicAdd(&counts[dst], 1);
}

// ---------------- Kernels 4a/4b/4c: two-level exclusive scan ----------------
__global__ __launch_bounds__(256) void scanA_kernel(const int* __restrict__ counts,
                                                    int* __restrict__ local,
                                                    int* __restrict__ bsum) {
    const int t = threadIdx.x, lane = t & 63, w = t >> 6;
    const int i = blockIdx.x * 256 + t;
    const int v = (i < N_NODES) ? counts[i] : 0;
    const int inc = wave_incl_scan(v, lane);
    __shared__ int wt[4];
    if (lane == 63) wt[w] = inc;
    __syncthreads();
    int base = 0;
    #pragma unroll
    for (int k = 0; k < 3; ++k) if (k < w) base += wt[k];
    if (i < N_NODES) local[i] = base + inc - v;       // block-local exclusive
    if (t == 255) bsum[blockIdx.x] = base + inc;      // block total
}

__global__ __launch_bounds__(256) void scanB_kernel(const int* __restrict__ bsum,
                                                    int* __restrict__ boff) {
    const int t = threadIdx.x, lane = t & 63, w = t >> 6;
    const int v = (t < NB_SCAN) ? bsum[t] : 0;
    const int inc = wave_incl_scan(v, lane);
    __shared__ int wt[4];
    if (lane == 63) wt[w] = inc;
    __syncthreads();
    int base = 0;
    #pragma unroll
    for (int k = 0; k < 3; ++k) if (k < w) base += wt[k];
    if (t < NB_SCAN) boff[t] = base + inc - v;        // exclusive block offset
}

__global__ __launch_bounds__(256) void scanC_kernel(const int* __restrict__ local,
                                                    const int* __restrict__ boff,
                                                    int* __restrict__ offsets,
                                                    int* __restrict__ cursor) {
    const int i = blockIdx.x * 256 + threadIdx.x;
    if (i < N_NODES) {
        const int o = local[i] + boff[blockIdx.x];
        offsets[i] = o;
        cursor[i]  = o;
    }
    if (i == 0) offsets[N_NODES] = E_TOT;
}

// ---------------- Kernel 5: fill CSR payload: src + exp-scores ----------------
__global__ void fill_kernel(const int* __restrict__ ei,
                            const float* __restrict__ a_s,
                            const float* __restrict__ a_d,
                            int* __restrict__ cursor,
                            int* __restrict__ sorted_src,
                            float4* __restrict__ sorted_ex) {
    const int e = blockIdx.x * blockDim.x + threadIdx.x;
    if (e >= E_TOT) return;
    int src, dst;
    if (e < N_EDGES) { src = ei[e]; dst = ei[N_EDGES + e]; }
    else             { src = dst = e - N_EDGES; }
    const float4 as = *reinterpret_cast<const float4*>(&a_s[src * HEADS]);
    const float4 ad = *reinterpret_cast<const float4*>(&a_d[dst * HEADS]);
    float4 ex;
    ex.x = expf(leaky(as.x + ad.x));
    ex.y = expf(leaky(as.y + ad.y));
    ex.z = expf(leaky(as.z + ad.z));
    ex.w = expf(leaky(as.w + ad.w));
    const int slot = atomicAdd(&cursor[dst], 1);
    sorted_src[slot] = src;
    sorted_ex[slot]  = ex;
}

// ---------------- Kernel 6: gather-aggregate, one wave per dst, 2 edges/round
__global__ __launch_bounds__(256) void gather_kernel(const int* __restrict__ sorted_src,
                                                     const float* __restrict__ sorted_ex,
                                                     const int* __restrict__ offsets,
                                                     const unsigned short* __restrict__ h_bf,
                                                     const float* __restrict__ bias,
                                                     float* __restrict__ out) {
    const int dst  = (blockIdx.x * 256 + threadIdx.x) >> 6;
    const int lane = threadIdx.x & 63;
    if (dst >= N_NODES) return;
    const int half = lane >> 5;
    const int il   = lane & 31;
    const int hd   = il >> 3;

    const int beg = __builtin_amdgcn_readfirstlane(offsets[dst]);
    const int end = __builtin_amdgcn_readfirstlane(offsets[dst + 1]);

    float a0 = 0.f, a1 = 0.f, a2 = 0.f, a3 = 0.f;
    float a4 = 0.f, a5 = 0.f, a6 = 0.f, a7 = 0.f;
    float dsum = 0.f;

    auto body = [&](int slot) {
        const int   src = sorted_src[slot];
        const float ex  = sorted_ex[slot * 4 + hd];
        const uint4 hv  = *reinterpret_cast<const uint4*>(&h_bf[src * HF + il * 8]);
        a0 = fmaf(ex, bf_lo(hv.x), a0); a1 = fmaf(ex, bf_hi(hv.x), a1);
        a2 = fmaf(ex, bf_lo(hv.y), a2); a3 = fmaf(ex, bf_hi(hv.y), a3);
        a4 = fmaf(ex, bf_lo(hv.z), a4); a5 = fmaf(ex, bf_hi(hv.z), a5);
        a6 = fmaf(ex, bf_lo(hv.w), a6); a7 = fmaf(ex, bf_hi(hv.w), a7);
        dsum += ex;
    };

    int j = beg;
    for (; j + 3 < end; j += 4) {        // 4 edges per iteration (2 per half)
        body(j + half);
        body(j + 2 + half);
    }
    for (; j + 1 < end; j += 2) body(j + half);
    if (j < end && half == 0) body(j);   // odd tail: half 0 only

    a0 += __shfl_xor(a0, 32); a1 += __shfl_xor(a1, 32);
    a2 += __shfl_xor(a2, 32); a3 += __shfl_xor(a3, 32);
    a4 += __shfl_xor(a4, 32); a5 += __shfl_xor(a5, 32);
    a6 += __shfl_xor(a6, 32); a7 += __shfl_xor(a7, 32);
    dsum += __shfl_xor(dsum, 32);

    const float inv = 1.f / (dsum + 1e-16f);
    const int eo = il * 8 + half * 4;    // element offset within row
    const float4 bv = *reinterpret_cast<const float4*>(&bias[eo]);
    float4 o;
    o.x = (half ? a4 : a0) * inv + bv.x;
    o.y = (half ? a5 : a1) * inv + bv.y;
    o.z = (half ? a6 : a2) * inv + bv.z;
    o.w = (half ? a7 : a3) * inv + bv.w;
    *reinterpret_cast<float4*>(&out[dst * HF + eo]) = o;
}

extern "C" void kernel_launch(void* const* d_in, const int* in_sizes, int n_in,
                              void* d_out, int out_size, void* d_ws, size_t ws_size,
                              hipStream_t stream) {
    const float* x       = (const float*)d_in[0];
    const int*   ei      = (const int*)d_in[1];   // [2, E]: src row then dst row
    const float* W       = (const float*)d_in[2];
    const float* att_src = (const float*)d_in[3];
    const float* att_dst = (const float*)d_in[4];
    const float* bias    = (const float*)d_in[5];
    float* out = (float*)d_out;

    char* ws = (char*)d_ws;
    unsigned short* h_bf = (unsigned short*)(ws);        // 25,600,000 B
    float*  a_s        = (float*) (ws + 25600000);       //    800,000 B
    float*  a_d        = (float*) (ws + 26400000);       //    800,000 B
    int*    counts     = (int*)   (ws + 27200000);       //    200,000 B
    int*    offsets    = (int*)   (ws + 27400000);       //    200,004 B
    int*    cursor     = (int*)   (ws + 27600016);       //    200,000 B
    int*    sorted_src = (int*)   (ws + 27800016);       //  6,600,000 B
    float4* sorted_ex  = (float4*)(ws + 34400016);       // 26,400,000 B
    int*    local      = (int*)   (ws + 60800016);       //    200,000 B
    int*    bsum       = (int*)   (ws + 61000016);       //        784 B
    int*    boff       = (int*)   (ws + 61000800);       //        784 B → 61 MB total

    gemm_kernel<<<(N_NODES + 63) / 64, 256, 0, stream>>>(x, W, att_src, att_dst,
                                                         h_bf, a_s, a_d);
    zero_kernel<<<(N_NODES + 255) / 256, 256, 0, stream>>>(counts);
    hist_kernel<<<(E_TOT + 255) / 256, 256, 0, stream>>>(ei, counts);
    scanA_kernel<<<NB_SCAN, 256, 0, stream>>>(counts, local, bsum);
    scanB_kernel<<<1, 256, 0, stream>>>(bsum, boff);
    scanC_kernel<<<NB_SCAN, 256, 0, stream>>>(local, boff, offsets, cursor);
    fill_kernel<<<(E_TOT + 255) / 256, 256, 0, stream>>>(ei, a_s, a_d, cursor,
                                                         sorted_src, sorted_ex);
    const long total_threads = (long)N_NODES * 64;
    gather_kernel<<<(int)((total_threads + 255) / 256), 256, 0, stream>>>(
        sorted_src, (const float*)sorted_ex, offsets, h_bf, bias, out);
}